// Round 19
// baseline (148.136 us; speedup 1.0000x reference)
//
#include <hip/hip_runtime.h>

#define NA 1000
#define NCH 6
#define CH0 168                // chunks: 168,168,168,168,168,160 (all %8==0)
#define ND 513
#define CROP 362
#define TOP 75                 // (512-362)/2
#define NPIX (CROP * CROP)     // 131044
#define TI 32                  // tile rows (i)
#define TJ 16                  // tile cols (j)
#define NTI 12                 // ceil(362/32)
#define NTJ 23                 // ceil(362/16)
#define GRP 8                  // angles per staged group
#define WIN 40                 // cells per window (span <= 37.5)
#define SLOTS (GRP * WIN)      // 320 cells per buffer

// rotation by 2*dtheta = 2*pi/1000 (double-evaluated literals)
#define C2R 0.9999802608561400f
#define S2R 0.0062831439655596f

typedef __fp16 half2_t __attribute__((ext_vector_type(2)));

#if defined(__has_builtin)
#if __has_builtin(__builtin_amdgcn_global_load_lds)
#define HAS_GLL 1
#endif
#endif

#ifdef HAS_GLL
// async global->LDS, 16B/lane; LDS dest wave-uniform (HW adds lane*16)
#define GLL(G, L) __builtin_amdgcn_global_load_lds(                        \
    (const __attribute__((address_space(1))) void*)(G),                   \
    (__attribute__((address_space(3))) void*)(L), 16, 0, 0)
#endif

// Static device buffers, fully rewritten every call (deterministic).
// g_cell[a*ND+d] = 16 B: 8 f16 batch values (unpaired).
__device__ float2 g_tab[NA];
__device__ uint4  g_cell[(size_t)NA * ND];
__device__ float  g_part[(size_t)NCH * 8 * NPIX];

__global__ void table_kernel() {
    int a = blockIdx.x * blockDim.x + threadIdx.x;
    if (a >= NA) return;
    double th = (double)a * (3.14159265358979323846 / (double)NA);
    float delta_f = (float)(2.0 * 0.13 / (double)(ND - 1));
    double inv = 1.0 / (double)delta_f;
    g_tab[a] = make_float2((float)(cos(th) * inv), (float)(sin(th) * inv));
}

// x[b][a][d] (b-major, f32) -> g_cell (8 f16 per det cell), RNE.
__global__ void pack_kernel(const float* __restrict__ x) {
    int t = blockIdx.x * blockDim.x + threadIdx.x;   // t = a*ND + d
    if (t >= NA * ND) return;
    const int S = NA * ND;
    unsigned int w[4];
    #pragma unroll
    for (int b = 0; b < 4; ++b) {
        half2_t h;
        h.x = (__fp16)x[(size_t)(2 * b) * S + t];
        h.y = (__fp16)x[(size_t)(2 * b + 1) * S + t];
        __builtin_memcpy(&w[b], &h, 4);
    }
    g_cell[t] = make_uint4(w[0], w[1], w[2], w[3]);
}

__device__ __forceinline__ float dot2(unsigned int pair, half2_t wp, float acc) {
    half2_t h; __builtin_memcpy(&h, &pair, 4);
    float d;
    asm("v_dot2_f32_f16 %0, %1, %2, %3" : "=v"(d) : "v"(h), "v"(wp), "v"(acc));
    return d;
}

#define ROT2(CC, SS) { float oc=CC, os=SS; CC = fmaf(oc, C2R, -(os*S2R)); SS = fmaf(oc, S2R, os*C2R); }

// grid (23,12,6); block 256 = 4 waves; tile 32(i) x 16(j); each thread owns
// 2 j-adjacent pixels x 8 batches. Per angle: 3 contiguous ds_read_b128 feed
// both pixels. pb-pa = sin*512/511 can slightly exceed 1 cell: the select is
// on pbm = pb-floor(pa) with wb snapped to 1 when pbm >= 2 (error <= 2e-3 of
// one angle's term — negligible after pi/1000 scaling).
__global__ __launch_bounds__(256, 8) void bp_kernel() {
    __shared__ uint4 s_win[2][SLOTS];             // 10 KB
    __shared__ alignas(16) int s_base[CH0];       // 672 B

    int ch  = blockIdx.z;
    int A0  = ch * CH0;
    int len = min(CH0, NA - A0);         // 168 or 160
    int ngrp = len >> 3;
    int tid = threadIdx.x;
    int bi  = blockIdx.y, bj = blockIdx.x;

    const float step = (float)(0.26 / 511.0);

    // ---- per-angle window bases (corner-min p over 32x16 tile, 2-cell guard) ----
    float Xa = fmaf((float)(TOP + bi * TI),          step, -0.13f);
    float Xb = fmaf((float)(TOP + bi * TI + TI - 1), step, -0.13f);
    float Ya = fmaf((float)(TOP + bj * TJ),          step, -0.13f);
    float Yb = fmaf((float)(TOP + bj * TJ + TJ - 1), step, -0.13f);
    for (int t = tid; t < len; t += 256) {
        float2 cs = g_tab[A0 + t];
        float p0 = fmaf(Xa, cs.x, fmaf(Ya, cs.y, 256.0f));
        float p1 = fmaf(Xb, cs.x, fmaf(Ya, cs.y, 256.0f));
        float p2 = fmaf(Xa, cs.x, fmaf(Yb, cs.y, 256.0f));
        float p3 = fmaf(Xb, cs.x, fmaf(Yb, cs.y, 256.0f));
        float pm = fminf(fminf(p0, p1), fminf(p2, p3)) - 2.0f;
        int b = (int)floorf(pm);
        b = b < 0 ? 0 : b;
        b = b > (ND - WIN) ? (ND - WIN) : b;   // [0, 473]
        s_base[t] = b;
    }
    __syncthreads();

    // ---- pixel coords: wave wv owns 8(i) x 8 j-pairs ----
    int wv = tid >> 6, lane = tid & 63;
    int i = bi * TI + wv * 8 + (lane >> 3);    // -> X
    int j = bj * TJ + (lane & 7) * 2;          // -> Y (pixel a); pixel b = j+1
    int ic  = min(i, CROP - 1);
    int jc  = min(j, CROP - 1);
    int jc2 = min(j + 1, CROP - 1);
    float X = fmaf((float)(TOP + ic), step, -0.13f);
    float Y = fmaf((float)(TOP + jc), step, -0.13f);
    float stepdp = step * (float)(jc2 - jc);   // 0 when clamped equal

    // ---- 2 rotation chains stepping 2*dtheta ----
    float2 t0 = g_tab[A0 + 0], t1 = g_tab[A0 + 1];
    float c_0 = t0.x, s_0 = t0.y, c_1 = t1.x, s_1 = t1.y;

    // ---- staging: 320 cells; wave wv cells [64wv,64wv+64), wave 0 also [256,320) ----
#ifdef HAS_GLL
#define STAGE(GG, DST)                                                        \
    {                                                                         \
        int cid = (wv << 6) + lane;                                           \
        int aa = cid / WIN; int col = cid - aa * WIN;                         \
        int ag = (GG) + aa;                                                   \
        GLL(g_cell + (size_t)(A0 + ag) * ND + (s_base[ag] + col), (DST) + (wv << 6)); \
        if (wv == 0) {                                                        \
            int c2 = 256 + lane;                                              \
            int a2 = c2 / WIN; int col2 = c2 - a2 * WIN;                      \
            int ag2 = (GG) + a2;                                              \
            GLL(g_cell + (size_t)(A0 + ag2) * ND + (s_base[ag2] + col2), (DST) + 256); \
        }                                                                     \
    }
#else
    uint4 rs0, rs1;
#define STAGE(GG, DST)                                                        \
    {                                                                         \
        int aa = tid / WIN; int col = tid - aa * WIN;                         \
        rs0 = g_cell[(size_t)(A0 + (GG) + aa) * ND + s_base[(GG) + aa] + col];\
        if (tid < 64) {                                                       \
            int c2 = 256 + tid;                                              \
            int a2 = c2 / WIN; int col2 = c2 - a2 * WIN;                      \
            rs1 = g_cell[(size_t)(A0 + (GG) + a2) * ND + s_base[(GG) + a2] + col2]; \
        }                                                                     \
    }
#define STAGE_W(DST)                                                          \
    {                                                                         \
        (DST)[tid] = rs0;                                                     \
        if (tid < 64) (DST)[256 + tid] = rs1;                                 \
    }
#endif

    // ---- prologue: stage group 0 into buffer 0 ----
#ifdef HAS_GLL
    STAGE(0, &s_win[0][0])
#else
    STAGE(0, &s_win[0][0])
    STAGE_W(&s_win[0][0])
#endif
    __syncthreads();

    float acc0 = 0.f, acc1 = 0.f, acc2 = 0.f, acc3 = 0.f;
    float acc4 = 0.f, acc5 = 0.f, acc6 = 0.f, acc7 = 0.f;
    float bcc0 = 0.f, bcc1 = 0.f, bcc2 = 0.f, bcc3 = 0.f;
    float bcc4 = 0.f, bcc5 = 0.f, bcc6 = 0.f, bcc7 = 0.f;

#define LBODY(K, BASE, CC, SS)                                                \
    {                                                                         \
        float p  = fmaf(X, CC, fmaf(Y, SS, 256.0f));                          \
        float fa = floorf(p);                                                 \
        float wa = p - fa;                                                    \
        half2_t wpa = __builtin_amdgcn_cvt_pkrtz(1.0f - wa, wa);              \
        int la = (int)fa - (BASE);                                            \
        const uint4* q = wbuf + (K) * WIN + la;                               \
        uint4 C0 = q[0], C1 = q[1], C2 = q[2];                                \
        float pb  = fmaf(SS, stepdp, p);                                      \
        float pbm = pb - fa;                   /* in [0, 2.002) */            \
        bool sel  = pbm >= 1.0f;                                              \
        float wb  = fminf(pbm - (sel ? 1.0f : 0.0f), 1.0f);                   \
        half2_t wpb = __builtin_amdgcn_cvt_pkrtz(1.0f - wb, wb);              \
        uint4 D0 = sel ? C1 : C0;                                             \
        uint4 D1 = sel ? C2 : C1;                                             \
        acc0 = dot2(__builtin_amdgcn_perm(C1.x, C0.x, 0x05040100u), wpa, acc0); \
        acc1 = dot2(__builtin_amdgcn_perm(C1.x, C0.x, 0x07060302u), wpa, acc1); \
        acc2 = dot2(__builtin_amdgcn_perm(C1.y, C0.y, 0x05040100u), wpa, acc2); \
        acc3 = dot2(__builtin_amdgcn_perm(C1.y, C0.y, 0x07060302u), wpa, acc3); \
        acc4 = dot2(__builtin_amdgcn_perm(C1.z, C0.z, 0x05040100u), wpa, acc4); \
        acc5 = dot2(__builtin_amdgcn_perm(C1.z, C0.z, 0x07060302u), wpa, acc5); \
        acc6 = dot2(__builtin_amdgcn_perm(C1.w, C0.w, 0x05040100u), wpa, acc6); \
        acc7 = dot2(__builtin_amdgcn_perm(C1.w, C0.w, 0x07060302u), wpa, acc7); \
        bcc0 = dot2(__builtin_amdgcn_perm(D1.x, D0.x, 0x05040100u), wpb, bcc0); \
        bcc1 = dot2(__builtin_amdgcn_perm(D1.x, D0.x, 0x07060302u), wpb, bcc1); \
        bcc2 = dot2(__builtin_amdgcn_perm(D1.y, D0.y, 0x05040100u), wpb, bcc2); \
        bcc3 = dot2(__builtin_amdgcn_perm(D1.y, D0.y, 0x07060302u), wpb, bcc3); \
        bcc4 = dot2(__builtin_amdgcn_perm(D1.z, D0.z, 0x05040100u), wpb, bcc4); \
        bcc5 = dot2(__builtin_amdgcn_perm(D1.z, D0.z, 0x07060302u), wpb, bcc5); \
        bcc6 = dot2(__builtin_amdgcn_perm(D1.w, D0.w, 0x05040100u), wpb, bcc6); \
        bcc7 = dot2(__builtin_amdgcn_perm(D1.w, D0.w, 0x07060302u), wpb, bcc7); \
    }

    for (int g = 0; g < ngrp; ++g) {
        int cur = g & 1;
        bool have = (g + 1) < ngrp;
        if (have) STAGE((g + 1) << 3, &s_win[cur ^ 1][0])

        const uint4* wbuf = s_win[cur];
        int gb = g << 3;
        int4 q0 = *(const int4*)(s_base + gb);
        int4 q1 = *(const int4*)(s_base + gb + 4);
        int B0 = __builtin_amdgcn_readfirstlane(q0.x);
        int B1 = __builtin_amdgcn_readfirstlane(q0.y);
        int B2 = __builtin_amdgcn_readfirstlane(q0.z);
        int B3 = __builtin_amdgcn_readfirstlane(q0.w);
        int B4 = __builtin_amdgcn_readfirstlane(q1.x);
        int B5 = __builtin_amdgcn_readfirstlane(q1.y);
        int B6 = __builtin_amdgcn_readfirstlane(q1.z);
        int B7 = __builtin_amdgcn_readfirstlane(q1.w);

        LBODY(0, B0, c_0, s_0)
        LBODY(1, B1, c_1, s_1)
        ROT2(c_0, s_0) ROT2(c_1, s_1)
        LBODY(2, B2, c_0, s_0)
        LBODY(3, B3, c_1, s_1)
        ROT2(c_0, s_0) ROT2(c_1, s_1)
        LBODY(4, B4, c_0, s_0)
        LBODY(5, B5, c_1, s_1)
        ROT2(c_0, s_0) ROT2(c_1, s_1)
        LBODY(6, B6, c_0, s_0)
        LBODY(7, B7, c_1, s_1)
        ROT2(c_0, s_0) ROT2(c_1, s_1)

#ifndef HAS_GLL
        if (have) STAGE_W(&s_win[cur ^ 1][0])
#endif
        __syncthreads();
    }
#undef LBODY

    if (i < CROP) {
        float* p0 = g_part + (size_t)ch * 8 * NPIX + (size_t)i * CROP;
        if (j < CROP) {
            p0[0 * NPIX + j] = acc0; p0[1 * NPIX + j] = acc1;
            p0[2 * NPIX + j] = acc2; p0[3 * NPIX + j] = acc3;
            p0[4 * NPIX + j] = acc4; p0[5 * NPIX + j] = acc5;
            p0[6 * NPIX + j] = acc6; p0[7 * NPIX + j] = acc7;
        }
        if (j + 1 < CROP) {
            int j2 = j + 1;
            p0[0 * NPIX + j2] = bcc0; p0[1 * NPIX + j2] = bcc1;
            p0[2 * NPIX + j2] = bcc2; p0[3 * NPIX + j2] = bcc3;
            p0[4 * NPIX + j2] = bcc4; p0[5 * NPIX + j2] = bcc5;
            p0[6 * NPIX + j2] = bcc6; p0[7 * NPIX + j2] = bcc7;
        }
    }
}

// out[b][pix] = sum_ch part[ch][b][pix] * pi/NA
__global__ void combine_kernel(float* __restrict__ out) {
    int t = blockIdx.x * 256 + threadIdx.x;      // t over 8*NPIX, batch-major
    if (t >= 8 * NPIX) return;
    const float scale = (float)(3.14159265358979323846 / 1000.0);
    float s = 0.f;
    #pragma unroll
    for (int ch = 0; ch < NCH; ++ch) s += g_part[(size_t)ch * 8 * NPIX + t];
    out[t] = s * scale;
}

extern "C" void kernel_launch(void* const* d_in, const int* in_sizes, int n_in,
                              void* d_out, int out_size, void* d_ws, size_t ws_size,
                              hipStream_t stream) {
    const float* x = (const float*)d_in[0];
    float* out = (float*)d_out;

    table_kernel<<<(NA + 255) / 256, 256, 0, stream>>>();
    pack_kernel<<<(NA * ND + 255) / 256, 256, 0, stream>>>(x);

    dim3 bgrid(NTJ, NTI, NCH);   // 23 x 12 x 6 = 1656 blocks
    bp_kernel<<<bgrid, 256, 0, stream>>>();

    combine_kernel<<<(8 * NPIX + 255) / 256, 256, 0, stream>>>(out);
}